// Round 3
// baseline (3498.452 us; speedup 1.0000x reference)
//
#include <hip/hip_runtime.h>
#include <hip/hip_bf16.h>
#include <cmath>

namespace {

constexpr int LAYERS = 12;
constexpr int H   = 768;
constexpr int NH  = 12;
constexpr int DH  = 64;
constexpr int FF  = 3072;
constexpr int V   = 21128;
constexpr int S   = 512;
constexpr int B   = 8;
constexpr int M   = B * S;            // 4096 tokens
constexpr int SEP = 102;
constexpr int NPAD = 21248;           // V padded to multiple of 128
constexpr int NT64 = NPAD / 64;       // 332 column half-tiles for logits
constexpr int QKVN = 3 * H;           // 2304 fused QKV output columns
constexpr size_t MHc = (size_t)M * H;

typedef __attribute__((ext_vector_type(8))) short short8;
typedef __attribute__((ext_vector_type(4))) float floatx4;

__device__ __forceinline__ float geluf(float x) {
  return 0.5f * x * (1.0f + erff(x * 0.70710678118654752f));
}

__device__ __forceinline__ void gload16(const void* g, void* l) {
  __builtin_amdgcn_global_load_lds(
      (const __attribute__((address_space(1))) void*)g,
      (__attribute__((address_space(3))) void*)l, 16, 0, 0);
}

__device__ __forceinline__ unsigned short f2bf(float f) {
  __hip_bfloat16 h = __float2bfloat16(f);
  return *reinterpret_cast<unsigned short*>(&h);
}

__device__ __forceinline__ float block_sum256(float v, float* red) {
  int tid = threadIdx.x;
  red[tid] = v; __syncthreads();
  for (int s2 = 128; s2 > 0; s2 >>= 1) {
    if (tid < s2) red[tid] += red[tid + s2];
    __syncthreads();
  }
  float r = red[0];
  __syncthreads();
  return r;
}

__device__ __forceinline__ float block_max256(float v, float* red) {
  int tid = threadIdx.x;
  red[tid] = v; __syncthreads();
  for (int s2 = 128; s2 > 0; s2 >>= 1) {
    if (tid < s2) red[tid] = fmaxf(red[tid], red[tid + s2]);
    __syncthreads();
  }
  float r = red[0];
  __syncthreads();
  return r;
}

// ---------------- sep position per batch row ----------------
__global__ void sep_kernel(const int* __restrict__ ids, int* __restrict__ sep) {
  int b = blockIdx.x;
  __shared__ int red[256];
  int m = S - 1;
  for (int s = threadIdx.x; s < S; s += 256)
    if (ids[b * S + s] == SEP) m = min(m, s);
  red[threadIdx.x] = m; __syncthreads();
  for (int s2 = 128; s2 > 0; s2 >>= 1) {
    if (threadIdx.x < s2) red[threadIdx.x] = min(red[threadIdx.x], red[threadIdx.x + s2]);
    __syncthreads();
  }
  if (threadIdx.x == 0) sep[b] = red[0];
}

// ---------------- weight transpose + f32->bf16: W[K,N] -> Wt[Npad,K] ----------------
__global__ __launch_bounds__(256) void transpose_kernel(
    const float* __restrict__ W, __hip_bfloat16* __restrict__ Wt,
    int K, int N, int Npad, size_t in_stride, size_t out_stride) {
  const float* Wz = W + (size_t)blockIdx.z * in_stride;
  __hip_bfloat16* Wtz = Wt + (size_t)blockIdx.z * out_stride;
  __shared__ float tile[32][33];
  int k0 = blockIdx.x * 32, n0 = blockIdx.y * 32;
  int tx = threadIdx.x & 31, ty = threadIdx.x >> 5;  // 32 x 8
  #pragma unroll
  for (int i = 0; i < 4; i++) {
    int kk = k0 + ty + i * 8, nn = n0 + tx;
    tile[ty + i * 8][tx] = (kk < K && nn < N) ? Wz[(size_t)kk * N + nn] : 0.f;
  }
  __syncthreads();
  #pragma unroll
  for (int i = 0; i < 4; i++) {
    int nn = n0 + ty + i * 8, kk = k0 + tx;
    if (nn < Npad && kk < K)
      Wtz[(size_t)nn * K + kk] = __float2bfloat16(tile[tx][ty + i * 8]);
  }
}

// ---------------- embedding + LN (writes f32 x and bf16 xb) ----------------
__global__ __launch_bounds__(256) void embed_kernel(
    const int* __restrict__ ids, const float* __restrict__ we,
    const float* __restrict__ pe, const float* __restrict__ te,
    const float* __restrict__ g, const float* __restrict__ bta,
    float* __restrict__ x, __hip_bfloat16* __restrict__ xb) {
  __shared__ float red[256];
  int tok = blockIdx.x;
  int s = tok % S;
  int id = ids[tok];
  float vals[3];
  #pragma unroll
  for (int i = 0; i < 3; i++) {
    int hh = threadIdx.x + i * 256;
    vals[i] = we[(size_t)id * H + hh] + pe[(size_t)s * H + hh] + te[hh];
  }
  float mean = block_sum256(vals[0] + vals[1] + vals[2], red) * (1.0f / H);
  float sq = 0.f;
  #pragma unroll
  for (int i = 0; i < 3; i++) { float d = vals[i] - mean; sq += d * d; }
  float var = block_sum256(sq, red) * (1.0f / H);
  float inv = rsqrtf(var + 1e-12f);
  #pragma unroll
  for (int i = 0; i < 3; i++) {
    int hh = threadIdx.x + i * 256;
    float o = (vals[i] - mean) * inv * g[hh] + bta[hh];
    x[(size_t)tok * H + hh] = o;
    xb[(size_t)tok * H + hh] = __float2bfloat16(o);
  }
}

// ---------------- residual + sum(NS slabs) + LN (writes f32 x and bf16 xb) ----------------
template <int NS>
__global__ __launch_bounds__(256) void add_ln_kernel(
    const float* __restrict__ resid, const float* __restrict__ t,
    const float* __restrict__ g, const float* __restrict__ bta,
    float* __restrict__ out, __hip_bfloat16* __restrict__ outb) {
  __shared__ float red[256];
  int tok = blockIdx.x;
  float vals[3];
  #pragma unroll
  for (int i = 0; i < 3; i++) {
    size_t idx = (size_t)tok * H + threadIdx.x + i * 256;
    float v = resid[idx];
    #pragma unroll
    for (int z = 0; z < NS; z++) v += t[z * MHc + idx];
    vals[i] = v;
  }
  float mean = block_sum256(vals[0] + vals[1] + vals[2], red) * (1.0f / H);
  float sq = 0.f;
  #pragma unroll
  for (int i = 0; i < 3; i++) { float d = vals[i] - mean; sq += d * d; }
  float var = block_sum256(sq, red) * (1.0f / H);
  float inv = rsqrtf(var + 1e-12f);
  #pragma unroll
  for (int i = 0; i < 3; i++) {
    int hh = threadIdx.x + i * 256;
    float o = (vals[i] - mean) * inv * g[hh] + bta[hh];
    out[(size_t)tok * H + hh] = o;
    outb[(size_t)tok * H + hh] = __float2bfloat16(o);
  }
}

// ---------------- MFMA bf16 GEMM: C = epi(A @ Bt^T + bias) ----------------
// 2-phase pipeline: double-buffered BK=32 LDS; stage tile t+1 BEFORE computing
// tile t; ONE __syncthreads() per K-step (its vmcnt(0) drains loads issued a
// full compute-phase earlier). EPI:
//  0 = f32 store (split-K slab per blockIdx.z); 1 = bf16 store;
//  2 = gelu + bf16 store; 3 = logits partials;
//  5 = fused QKV: col section 0 -> Cb (q), 1 -> Cb2 (k), 2 -> Cb3 as vt-transposed.
// SWZ: bijective XCD-aware block swizzle (each XCD owns contiguous col band).
template <int K, int N, int EPI, int SPLIT = 1, bool SWZ = false>
__global__ __launch_bounds__(256) void mfma_gemm(
    const short* __restrict__ A, const short* __restrict__ Bt,
    const float* __restrict__ bias,
    float* __restrict__ Cf, __hip_bfloat16* __restrict__ Cb,
    const int* __restrict__ labels, float2* __restrict__ partials,
    float* __restrict__ lablogit,
    __hip_bfloat16* __restrict__ Cb2, __hip_bfloat16* __restrict__ Cb3,
    const float* __restrict__ bias2, const float* __restrict__ bias3) {
  __shared__ __align__(16) short lds_a[2][128 * 32];
  __shared__ __align__(16) short lds_b[2][128 * 32];
  const int tid = threadIdx.x, lane = tid & 63, w = tid >> 6;
  const int wm = w >> 1, wn = w & 1;
  const int g = lane >> 4, c16 = lane & 15;
  const int srow = w * 32 + (lane >> 2);
  const int schunk = lane & 3;

  int bx = blockIdx.x, by = blockIdx.y;
  if constexpr (SWZ) {
    constexpr int NBX = N / 128;
    constexpr int GR = M / 128;          // 32 row tiles
    constexpr int NWG = NBX * GR;        // must be % 8 == 0
    static_assert(NWG % 8 == 0, "swizzle needs nwg %% 8 == 0");
    int lid = by * NBX + bx;
    int j = (lid & 7) * (NWG >> 3) + (lid >> 3);
    bx = j / GR; by = j % GR;
  }
  const int row0 = by * 128, col0 = bx * 128;

  floatx4 acc[4][4] = {};

  constexpr int Ks = K / SPLIT;
  constexpr int NTK = Ks / 32;
  const int koff = (SPLIT > 1) ? (int)blockIdx.z * Ks : 0;

  auto stage = [&](int buf, int k0) {
    #pragma unroll
    for (int j = 0; j < 2; j++) {
      int m = srow + j * 16;
      int cg = schunk ^ ((m >> 1) & 3);
      gload16(A + (size_t)(row0 + m) * K + (k0 + cg * 8),
              &lds_a[buf][w * 1024 + j * 512]);
      gload16(Bt + (size_t)(col0 + m) * K + (k0 + cg * 8),
              &lds_b[buf][w * 1024 + j * 512]);
    }
  };

  stage(0, koff);
  __syncthreads();   // prologue drain: buf 0 ready

  #pragma unroll 2
  for (int t = 0; t < NTK; ++t) {
    const int cur = t & 1;
    if (t + 1 < NTK) stage(cur ^ 1, koff + (t + 1) * 32);  // prefetch next tile
    short8 af[4], bfr[4];
    #pragma unroll
    for (int tt = 0; tt < 4; tt++) {
      int rm = wm * 64 + tt * 16 + c16;
      af[tt] = *(const short8*)(&lds_a[cur][rm * 32 + ((g ^ ((rm >> 1) & 3)) << 3)]);
      int rn = wn * 64 + tt * 16 + c16;
      bfr[tt] = *(const short8*)(&lds_b[cur][rn * 32 + ((g ^ ((rn >> 1) & 3)) << 3)]);
    }
    #pragma unroll
    for (int mt = 0; mt < 4; mt++)
      #pragma unroll
      for (int nt = 0; nt < 4; nt++)
        acc[mt][nt] = __builtin_amdgcn_mfma_f32_16x16x32_bf16(af[mt], bfr[nt], acc[mt][nt], 0, 0, 0);
    __syncthreads();   // drains prefetch (issued a full compute-phase ago) + read-done
  }

  if constexpr (EPI == 0) {
    float* Cfz = Cf + (size_t)blockIdx.z * ((size_t)M * N);
    #pragma unroll
    for (int mt = 0; mt < 4; mt++)
      #pragma unroll
      for (int r = 0; r < 4; r++) {
        int row = row0 + wm * 64 + mt * 16 + g * 4 + r;
        #pragma unroll
        for (int nt = 0; nt < 4; nt++) {
          int col = col0 + wn * 64 + nt * 16 + c16;
          float bb = (SPLIT == 1 || blockIdx.z == 0) ? bias[col] : 0.f;
          Cfz[(size_t)row * N + col] = acc[mt][nt][r] + bb;
        }
      }
  } else if constexpr (EPI == 1 || EPI == 2) {
    #pragma unroll
    for (int mt = 0; mt < 4; mt++)
      #pragma unroll
      for (int r = 0; r < 4; r++) {
        int row = row0 + wm * 64 + mt * 16 + g * 4 + r;
        #pragma unroll
        for (int nt = 0; nt < 4; nt++) {
          int col = col0 + wn * 64 + nt * 16 + c16;
          float vv = acc[mt][nt][r] + bias[col];
          if constexpr (EPI == 2) vv = geluf(vv);
          Cb[(size_t)row * N + col] = __float2bfloat16(vv);
        }
      }
  } else if constexpr (EPI == 5) {
    // fused QKV: whole 128-col block lies within one section (768 % 128 == 0)
    const int sect = col0 / H;           // 0=q, 1=k, 2=v
    const int lc0 = col0 - sect * H;
    if (sect < 2) {
      __hip_bfloat16* out = (sect == 0) ? Cb : Cb2;
      const float* bptr = (sect == 0) ? bias : bias2;
      #pragma unroll
      for (int mt = 0; mt < 4; mt++)
        #pragma unroll
        for (int r = 0; r < 4; r++) {
          int row = row0 + wm * 64 + mt * 16 + g * 4 + r;
          #pragma unroll
          for (int nt = 0; nt < 4; nt++) {
            int lc = lc0 + wn * 64 + nt * 16 + c16;
            out[(size_t)row * H + lc] = __float2bfloat16(acc[mt][nt][r] + bptr[lc]);
          }
        }
    } else {
      unsigned short* vt = (unsigned short*)Cb3;
      #pragma unroll
      for (int mt = 0; mt < 4; mt++) {
        int row = row0 + wm * 64 + mt * 16 + g * 4;   // token for r=0
        int bb = row >> 9, s0 = row & 511;
        #pragma unroll
        for (int nt = 0; nt < 4; nt++) {
          int lc = lc0 + wn * 64 + nt * 16 + c16;
          int h = lc >> 6, d = lc & 63;
          float bcol = bias3[lc];
          uint2 u;
          unsigned short p0 = f2bf(acc[mt][nt][0] + bcol);
          unsigned short p1 = f2bf(acc[mt][nt][1] + bcol);
          unsigned short p2 = f2bf(acc[mt][nt][2] + bcol);
          unsigned short p3 = f2bf(acc[mt][nt][3] + bcol);
          u.x = (unsigned int)p0 | ((unsigned int)p1 << 16);
          u.y = (unsigned int)p2 | ((unsigned int)p3 << 16);
          *(uint2*)(vt + ((size_t)((bb * NH + h) * DH + d) << 9) + s0) = u;
        }
      }
    }
  } else {
    #pragma unroll
    for (int mt = 0; mt < 4; mt++)
      #pragma unroll
      for (int r = 0; r < 4; r++) {
        int row = row0 + wm * 64 + mt * 16 + g * 4 + r;
        int lab = labels[row];
        float vals[4];
        float rmax = -1e30f;
        #pragma unroll
        for (int nt = 0; nt < 4; nt++) {
          int col = col0 + wn * 64 + nt * 16 + c16;
          float vv = (col < V) ? (acc[mt][nt][r] + bias[col]) : -60000.0f;
          vals[nt] = vv;
          rmax = fmaxf(rmax, vv);
          if (col == lab) lablogit[row] = vv;
        }
        #pragma unroll
        for (int d = 1; d < 16; d <<= 1) rmax = fmaxf(rmax, __shfl_xor(rmax, d, 64));
        float se = 0.f;
        #pragma unroll
        for (int nt = 0; nt < 4; nt++) se += __expf(vals[nt] - rmax);
        #pragma unroll
        for (int d = 1; d < 16; d <<= 1) se += __shfl_xor(se, d, 64);
        if (c16 == 0)
          partials[(size_t)row * NT64 + (col0 >> 6) + wn] = make_float2(rmax, se);
      }
  }
}

// ---------------- MFMA flash attention ----------------
__global__ __launch_bounds__(256) void flash_attn(
    const short* __restrict__ q, const short* __restrict__ k,
    const short* __restrict__ vt, const int* __restrict__ sep,
    __hip_bfloat16* __restrict__ ctx) {
  constexpr int KT = 128;
  __shared__ __align__(16) short Qs[64 * 64];
  __shared__ __align__(16) short Ks[128 * 64];
  __shared__ __align__(16) short Vts[64 * 128];
  __shared__ __align__(16) short Pb[64 * 136];
  __shared__ __align__(16) float wm4[4][64];
  __shared__ __align__(16) float wl4[4][64];
  __shared__ __align__(16) float m_run[64], l_run[64], alpha_s[64], mnew_s[64];

  const int tid = threadIdx.x, lane = tid & 63, w = tid >> 6;
  const int g = lane >> 4, c16 = lane & 15;
  const int qt0 = blockIdx.x * 64, h = blockIdx.y, b = blockIdx.z;
  const int sepb = sep[b];

  if (tid < 64) { m_run[tid] = -1e30f; l_run[tid] = 0.f; }

  // stage Q tile [64 q][64 d], chunk-swizzled: slot = c ^ (row&7)
  #pragma unroll
  for (int t = 0; t < 2; t++) {
    int id = (w * 2 + t) * 64 + lane;
    int row = id >> 3, slot = id & 7;
    int c = slot ^ (row & 7);
    gload16(q + (size_t)(b * S + qt0 + row) * H + h * DH + c * 8,
            Qs + (w * 2 + t) * 512);
  }

  int niter = (qt0 + 64 + KT - 1) / KT;
  int sepit = (sepb >> 7) + 1;
  if (sepit > niter) niter = sepit;

  floatx4 accO[4] = {};
  short8 qf[4][2];

  for (int it = 0; it < niter; ++it) {
    int kk0 = it * KT;
    __syncthreads();   // prev iteration's LDS reads complete
    #pragma unroll
    for (int t = 0; t < 4; t++) {
      int id = (w * 4 + t) * 64 + lane;
      {
        int row = id >> 3, slot = id & 7, c = slot ^ (row & 7);
        gload16(k + (size_t)(b * S + kk0 + row) * H + h * DH + c * 8,
                Ks + (w * 4 + t) * 512);
      }
      {
        int row = id >> 4, slot = id & 15, c = slot ^ (row & 15);
        gload16(vt + (size_t)((b * NH + h) * DH + row) * S + kk0 + c * 8,
                Vts + (w * 4 + t) * 512);
      }
    }
    __syncthreads();   // staging complete (drains vmcnt)

    if (it == 0) {
      #pragma unroll
      for (int nt = 0; nt < 4; nt++)
        #pragma unroll
        for (int st = 0; st < 2; st++) {
          int qq = nt * 16 + c16;
          int slot = (st * 4 + g) ^ (qq & 7);
          qf[nt][st] = *(const short8*)(Qs + qq * 64 + slot * 8);
        }
    }

    // Sc^T [128 kk][64 q]
    floatx4 accS[2][4] = {};
    #pragma unroll
    for (int st = 0; st < 2; st++) {
      short8 af[2];
      #pragma unroll
      for (int mt = 0; mt < 2; mt++) {
        int kkr = w * 32 + mt * 16 + c16;
        int slot = (st * 4 + g) ^ (kkr & 7);
        af[mt] = *(const short8*)(Ks + kkr * 64 + slot * 8);
      }
      #pragma unroll
      for (int mt = 0; mt < 2; mt++)
        #pragma unroll
        for (int nt = 0; nt < 4; nt++)
          accS[mt][nt] = __builtin_amdgcn_mfma_f32_16x16x32_bf16(
              af[mt], qf[nt][st], accS[mt][nt], 0, 0, 0);
    }

    // mask + scale; per-lane max per q
    float sc[2][4][4];
    float pm[4] = {-1e30f, -1e30f, -1e30f, -1e30f};
    #pragma unroll
    for (int mt = 0; mt < 2; mt++)
      #pragma unroll
      for (int nt = 0; nt < 4; nt++)
        #pragma unroll
        for (int r = 0; r < 4; r++) {
          int kkg = kk0 + w * 32 + mt * 16 + g * 4 + r;
          int qg = qt0 + nt * 16 + c16;
          bool allowed = (kkg <= qg) || (qg <= sepb && kkg <= sepb);
          float vv = accS[mt][nt][r] * 0.125f + (allowed ? 0.f : -1e4f);
          sc[mt][nt][r] = vv;
          pm[nt] = fmaxf(pm[nt], vv);
        }
    #pragma unroll
    for (int nt = 0; nt < 4; nt++) {
      pm[nt] = fmaxf(pm[nt], __shfl_xor(pm[nt], 16, 64));
      pm[nt] = fmaxf(pm[nt], __shfl_xor(pm[nt], 32, 64));
    }
    if (lane < 16) {
      #pragma unroll
      for (int nt = 0; nt < 4; nt++) wm4[w][nt * 16 + c16] = pm[nt];
    }
    __syncthreads();
    if (tid < 64) {
      float mit = fmaxf(fmaxf(wm4[0][tid], wm4[1][tid]), fmaxf(wm4[2][tid], wm4[3][tid]));
      float mold = m_run[tid];
      float mnew = fmaxf(mold, mit);
      float al = __expf(mold - mnew);
      m_run[tid] = mnew;
      alpha_s[tid] = al;
      mnew_s[tid] = mnew;
      l_run[tid] *= al;
    }
    __syncthreads();

    // P = exp(sc - mnew); write P^T to Pb[q][kk]
    float psum[4] = {};
    #pragma unroll
    for (int mt = 0; mt < 2; mt++)
      #pragma unroll
      for (int nt = 0; nt < 4; nt++) {
        int qg = nt * 16 + c16;
        float mn = mnew_s[qg];
        unsigned short pk[4];
        #pragma unroll
        for (int r = 0; r < 4; r++) {
          float p = __expf(sc[mt][nt][r] - mn);
          psum[nt] += p;
          pk[r] = f2bf(p);
        }
        int kb = w * 32 + mt * 16 + g * 4;
        uint2 u;
        u.x = (unsigned int)pk[0] | ((unsigned int)pk[1] << 16);
        u.y = (unsigned int)pk[2] | ((unsigned int)pk[3] << 16);
        *(uint2*)(Pb + qg * 136 + kb) = u;
      }
    #pragma unroll
    for (int nt = 0; nt < 4; nt++) {
      psum[nt] += __shfl_xor(psum[nt], 16, 64);
      psum[nt] += __shfl_xor(psum[nt], 32, 64);
    }
    if (lane < 16) {
      #pragma unroll
      for (int nt = 0; nt < 4; nt++) wl4[w][nt * 16 + c16] = psum[nt];
    }
    {
      float4 a4 = *(const float4*)(alpha_s + w * 16 + g * 4);
      #pragma unroll
      for (int nt = 0; nt < 4; nt++) {
        accO[nt][0] *= a4.x; accO[nt][1] *= a4.y;
        accO[nt][2] *= a4.z; accO[nt][3] *= a4.w;
      }
    }
    __syncthreads();   // Pb + wl4 visible
    if (tid < 64)
      l_run[tid] += wl4[0][tid] + wl4[1][tid] + wl4[2][tid] + wl4[3][tid];

    // O[64 q][64 d] += P · V^T
    #pragma unroll
    for (int st = 0; st < 4; st++) {
      short8 pf = *(const short8*)(Pb + (w * 16 + c16) * 136 + st * 32 + g * 8);
      #pragma unroll
      for (int nt = 0; nt < 4; nt++) {
        int d = nt * 16 + c16;
        int slot = (st * 4 + g) ^ (d & 15);
        short8 vf = *(const short8*)(Vts + d * 128 + slot * 8);
        accO[nt] = __builtin_amdgcn_mfma_f32_16x16x32_bf16(pf, vf, accO[nt], 0, 0, 0);
      }
    }
  }

  __syncthreads();
  float4 lv = *(const float4*)(l_run + w * 16 + g * 4);
  float linv[4] = {1.0f / lv.x, 1.0f / lv.y, 1.0f / lv.z, 1.0f / lv.w};
  #pragma unroll
  for (int r = 0; r < 4; r++) {
    int row = b * S + qt0 + w * 16 + g * 4 + r;
    #pragma unroll
    for (int nt = 0; nt < 4; nt++)
      ctx[(size_t)row * H + h * DH + nt * 16 + c16] =
          __float2bfloat16(accO[nt][r] * linv[r]);
  }
}

// ---------------- per-token nll + accumulate ----------------
__global__ __launch_bounds__(256) void loss_kernel(
    const float2* __restrict__ partials, const float* __restrict__ lablogit,
    const int* __restrict__ labels, float* __restrict__ acc) {
  int tok = blockIdx.x;
  if (labels[tok] < 0) return;
  __shared__ float red[256];
  float lm = -1e30f;
  for (int t = threadIdx.x; t < NT64; t += 256)
    lm = fmaxf(lm, partials[(size_t)tok * NT64 + t].x);
  float Mx = block_max256(lm, red);
  float ls = 0.f;
  for (int t = threadIdx.x; t < NT64; t += 256) {
    float2 p = partials[(size_t)tok * NT64 + t];
    ls += p.y * __expf(p.x - Mx);
  }
  float Ssum = block_sum256(ls, red);
  if (threadIdx.x == 0) {
    float nll = (Mx + logf(Ssum)) - lablogit[tok];
    atomicAdd(&acc[0], nll);
    atomicAdd(&acc[1], 1.0f);
  }
}

__global__ void finalize_kernel(const float* __restrict__ acc, float* __restrict__ out) {
  out[0] = acc[0] / fmaxf(acc[1], 1.0f);
}

}  // namespace

extern "C" void kernel_launch(void* const* d_in, const int* in_sizes, int n_in,
                              void* d_out, int out_size, void* d_ws, size_t ws_size,
                              hipStream_t stream) {
  const int*   input_ids = (const int*)d_in[0];
  const int*   labels    = (const int*)d_in[1];
  const float* word_emb  = (const float*)d_in[2];
  const float* pos_emb   = (const float*)d_in[3];
  const float* type_emb  = (const float*)d_in[4];
  const float* emb_ln_g  = (const float*)d_in[5];
  const float* emb_ln_b  = (const float*)d_in[6];
  const float* Wq = (const float*)d_in[7];
  const float* bq = (const float*)d_in[8];
  const float* Wk = (const float*)d_in[9];
  const float* bk = (const float*)d_in[10];
  const float* Wv = (const float*)d_in[11];
  const float* bv = (const float*)d_in[12];
  const float* Wo = (const float*)d_in[13];
  const float* bo = (const float*)d_in[14];
  const float* ln1_g = (const float*)d_in[15];
  const float* ln1_b = (const float*)d_in[16];
  const float* Wi = (const float*)d_in[17];
  const float* bi = (const float*)d_in[18];
  const float* Wd = (const float*)d_in[19];
  const float* bd = (const float*)d_in[20];
  const float* ln2_g = (const float*)d_in[21];
  const float* ln2_b = (const float*)d_in[22];
  const float* Wc = (const float*)d_in[23];
  const float* bc = (const float*)d_in[24];

  char* base = (char*)d_ws;
  size_t off = 0;
  auto alloc = [&](size_t bytes) -> void* {
    void* p = base + off;
    off = (off + bytes + 255) & ~(size_t)255;
    return p;
  };
  const size_t MH = (size_t)M * H;
  float*          x        = (float*)alloc(MH * 4);
  float*          t2       = (float*)alloc(MH * 4 * 4);     // 4 split-K slabs
  __hip_bfloat16* xb       = (__hip_bfloat16*)alloc(MH * 2);
  __hip_bfloat16* qb       = (__hip_bfloat16*)alloc(MH * 2);
  __hip_bfloat16* kb       = (__hip_bfloat16*)alloc(MH * 2);
  __hip_bfloat16* vt       = (__hip_bfloat16*)alloc((size_t)B * NH * DH * S * 2);
  __hip_bfloat16* ctxb     = (__hip_bfloat16*)alloc(MH * 2);
  __hip_bfloat16* t1b      = (__hip_bfloat16*)alloc((size_t)M * FF * 2);
  float2*         partials = (float2*)alloc((size_t)M * NT64 * 8);
  float*          lablogit = (float*)alloc((size_t)M * 4);
  float*          acc      = (float*)alloc(2 * 4);
  int*            sep      = (int*)alloc(B * 4);
  __hip_bfloat16* wqkv_t = (__hip_bfloat16*)alloc((size_t)LAYERS * QKVN * H * 2);
  __hip_bfloat16* wo_t = (__hip_bfloat16*)alloc((size_t)LAYERS * H * H * 2);
  __hip_bfloat16* wi_t = (__hip_bfloat16*)alloc((size_t)FF * H * 2);
  __hip_bfloat16* wd_t = (__hip_bfloat16*)alloc((size_t)H * FF * 2);
  __hip_bfloat16* wc_t = (__hip_bfloat16*)alloc((size_t)NPAD * H * 2);

  hipMemsetAsync(acc, 0, 2 * sizeof(float), stream);

  sep_kernel<<<B, 256, 0, stream>>>(input_ids, sep);
  embed_kernel<<<M, 256, 0, stream>>>(input_ids, word_emb, pos_emb, type_emb,
                                      emb_ln_g, emb_ln_b, x, xb);

  {
    dim3 tg(H / 32, H / 32, LAYERS);
    // fused QKV weight buffer: per layer rows [0,768)=Wq cols, [768,1536)=Wk, [1536,2304)=Wv
    transpose_kernel<<<tg, 256, 0, stream>>>(Wq, wqkv_t, H, H, H,
                                             (size_t)H * H, (size_t)QKVN * H);
    transpose_kernel<<<tg, 256, 0, stream>>>(Wk, wqkv_t + (size_t)H * H, H, H, H,
                                             (size_t)H * H, (size_t)QKVN * H);
    transpose_kernel<<<tg, 256, 0, stream>>>(Wv, wqkv_t + (size_t)2 * H * H, H, H, H,
                                             (size_t)H * H, (size_t)QKVN * H);
    transpose_kernel<<<tg, 256, 0, stream>>>(Wo, wo_t, H, H, H, (size_t)H * H, (size_t)H * H);
    dim3 tgc(H / 32, NPAD / 32, 1);
    transpose_kernel<<<tgc, 256, 0, stream>>>(Wc, wc_t, H, V, NPAD, 0, 0);
  }

  dim3 gQKV(QKVN / 128, M / 128);      // (18, 32) = 576 blocks
  dim3 gO(H / 128, M / 128, 2);        // split-K x2: 384 blocks
  dim3 gF(FF / 128, M / 128);          // (24, 32) = 768 blocks
  dim3 gD(H / 128, M / 128, 4);        // split-K x4: 768 blocks
  dim3 gAttn(S / 64, NH, B);           // 768 blocks

  for (int l = 0; l < LAYERS; l++) {
    transpose_kernel<<<dim3(H / 32, FF / 32, 1), 256, 0, stream>>>(
        Wi + (size_t)l * H * FF, wi_t, H, FF, FF, 0, 0);
    transpose_kernel<<<dim3(FF / 32, H / 32, 1), 256, 0, stream>>>(
        Wd + (size_t)l * FF * H, wd_t, FF, H, H, 0, 0);

    const short* xbs = (const short*)xb;
    // fused QKV: one GEMM, N=2304
    mfma_gemm<H, QKVN, 5><<<gQKV, 256, 0, stream>>>(
        xbs, (const short*)(wqkv_t + (size_t)l * QKVN * H), bq + (size_t)l * H,
        nullptr, qb, nullptr, nullptr, nullptr,
        kb, vt, bk + (size_t)l * H, bv + (size_t)l * H);
    flash_attn<<<gAttn, 256, 0, stream>>>(
        (const short*)qb, (const short*)kb, (const short*)vt, sep, ctxb);
    // O projection, split-K x2 into slabs t2[0..1]
    mfma_gemm<H, H, 0, 2><<<gO, 256, 0, stream>>>(
        (const short*)ctxb, (const short*)(wo_t + (size_t)l * H * H), bo + (size_t)l * H,
        t2, nullptr, nullptr, nullptr, nullptr,
        nullptr, nullptr, nullptr, nullptr);
    add_ln_kernel<2><<<M, 256, 0, stream>>>(x, t2, ln1_g + (size_t)l * H,
                                            ln1_b + (size_t)l * H, x, xb);
    mfma_gemm<H, FF, 2><<<gF, 256, 0, stream>>>(
        (const short*)xb, (const short*)wi_t, bi + (size_t)l * FF,
        nullptr, t1b, nullptr, nullptr, nullptr,
        nullptr, nullptr, nullptr, nullptr);
    // FFN down projection, split-K x4 into slabs t2[0..3]
    mfma_gemm<FF, H, 0, 4><<<gD, 256, 0, stream>>>(
        (const short*)t1b, (const short*)wd_t, bd + (size_t)l * H,
        t2, nullptr, nullptr, nullptr, nullptr,
        nullptr, nullptr, nullptr, nullptr);
    add_ln_kernel<4><<<M, 256, 0, stream>>>(x, t2, ln2_g + (size_t)l * H,
                                            ln2_b + (size_t)l * H, x, xb);
  }

  dim3 gV(NPAD / 128, M / 128);  // (166, 32)
  mfma_gemm<H, NPAD, 3, 1, true><<<gV, 256, 0, stream>>>(
      (const short*)xb, (const short*)wc_t, bc,
      nullptr, nullptr, labels, partials, lablogit,
      nullptr, nullptr, nullptr, nullptr);
  loss_kernel<<<M, 256, 0, stream>>>(partials, lablogit, labels, acc);
  finalize_kernel<<<1, 1, 0, stream>>>(acc, (float*)d_out);
}

// Round 4
// 3054.759 us; speedup vs baseline: 1.1452x; 1.1452x over previous
//
#include <hip/hip_runtime.h>
#include <hip/hip_bf16.h>
#include <cmath>

namespace {

constexpr int LAYERS = 12;
constexpr int H   = 768;
constexpr int NH  = 12;
constexpr int DH  = 64;
constexpr int FF  = 3072;
constexpr int V   = 21128;
constexpr int S   = 512;
constexpr int B   = 8;
constexpr int M   = B * S;            // 4096 tokens
constexpr int SEP = 102;
constexpr int NPAD = 21248;           // V padded to multiple of 128
constexpr int NT64 = NPAD / 64;       // 332 column half-tiles for logits
constexpr int QKVN = 3 * H;           // 2304 fused QKV output columns
constexpr size_t MHc = (size_t)M * H;

typedef __attribute__((ext_vector_type(8))) short short8;
typedef __attribute__((ext_vector_type(4))) float floatx4;

__device__ __forceinline__ float geluf(float x) {
  return 0.5f * x * (1.0f + erff(x * 0.70710678118654752f));
}

__device__ __forceinline__ void gload16(const void* g, void* l) {
  __builtin_amdgcn_global_load_lds(
      (const __attribute__((address_space(1))) void*)g,
      (__attribute__((address_space(3))) void*)l, 16, 0, 0);
}

__device__ __forceinline__ unsigned short f2bf(float f) {
  __hip_bfloat16 h = __float2bfloat16(f);
  return *reinterpret_cast<unsigned short*>(&h);
}

__device__ __forceinline__ float block_sum256(float v, float* red) {
  int tid = threadIdx.x;
  red[tid] = v; __syncthreads();
  for (int s2 = 128; s2 > 0; s2 >>= 1) {
    if (tid < s2) red[tid] += red[tid + s2];
    __syncthreads();
  }
  float r = red[0];
  __syncthreads();
  return r;
}

__device__ __forceinline__ float block_max256(float v, float* red) {
  int tid = threadIdx.x;
  red[tid] = v; __syncthreads();
  for (int s2 = 128; s2 > 0; s2 >>= 1) {
    if (tid < s2) red[tid] = fmaxf(red[tid], red[tid + s2]);
    __syncthreads();
  }
  float r = red[0];
  __syncthreads();
  return r;
}

// ---------------- sep position per batch row ----------------
__global__ void sep_kernel(const int* __restrict__ ids, int* __restrict__ sep) {
  int b = blockIdx.x;
  __shared__ int red[256];
  int m = S - 1;
  for (int s = threadIdx.x; s < S; s += 256)
    if (ids[b * S + s] == SEP) m = min(m, s);
  red[threadIdx.x] = m; __syncthreads();
  for (int s2 = 128; s2 > 0; s2 >>= 1) {
    if (threadIdx.x < s2) red[threadIdx.x] = min(red[threadIdx.x], red[threadIdx.x + s2]);
    __syncthreads();
  }
  if (threadIdx.x == 0) sep[b] = red[0];
}

// ---------------- weight transpose + f32->bf16: W[K,N] -> Wt[Npad,K] ----------------
__global__ __launch_bounds__(256) void transpose_kernel(
    const float* __restrict__ W, __hip_bfloat16* __restrict__ Wt,
    int K, int N, int Npad, size_t in_stride, size_t out_stride) {
  const float* Wz = W + (size_t)blockIdx.z * in_stride;
  __hip_bfloat16* Wtz = Wt + (size_t)blockIdx.z * out_stride;
  __shared__ float tile[32][33];
  int k0 = blockIdx.x * 32, n0 = blockIdx.y * 32;
  int tx = threadIdx.x & 31, ty = threadIdx.x >> 5;  // 32 x 8
  #pragma unroll
  for (int i = 0; i < 4; i++) {
    int kk = k0 + ty + i * 8, nn = n0 + tx;
    tile[ty + i * 8][tx] = (kk < K && nn < N) ? Wz[(size_t)kk * N + nn] : 0.f;
  }
  __syncthreads();
  #pragma unroll
  for (int i = 0; i < 4; i++) {
    int nn = n0 + ty + i * 8, kk = k0 + tx;
    if (nn < Npad && kk < K)
      Wtz[(size_t)nn * K + kk] = __float2bfloat16(tile[tx][ty + i * 8]);
  }
}

// ---------------- embedding + LN (writes f32 x and bf16 xb) ----------------
__global__ __launch_bounds__(256) void embed_kernel(
    const int* __restrict__ ids, const float* __restrict__ we,
    const float* __restrict__ pe, const float* __restrict__ te,
    const float* __restrict__ g, const float* __restrict__ bta,
    float* __restrict__ x, __hip_bfloat16* __restrict__ xb) {
  __shared__ float red[256];
  int tok = blockIdx.x;
  int s = tok % S;
  int id = ids[tok];
  float vals[3];
  #pragma unroll
  for (int i = 0; i < 3; i++) {
    int hh = threadIdx.x + i * 256;
    vals[i] = we[(size_t)id * H + hh] + pe[(size_t)s * H + hh] + te[hh];
  }
  float mean = block_sum256(vals[0] + vals[1] + vals[2], red) * (1.0f / H);
  float sq = 0.f;
  #pragma unroll
  for (int i = 0; i < 3; i++) { float d = vals[i] - mean; sq += d * d; }
  float var = block_sum256(sq, red) * (1.0f / H);
  float inv = rsqrtf(var + 1e-12f);
  #pragma unroll
  for (int i = 0; i < 3; i++) {
    int hh = threadIdx.x + i * 256;
    float o = (vals[i] - mean) * inv * g[hh] + bta[hh];
    x[(size_t)tok * H + hh] = o;
    xb[(size_t)tok * H + hh] = __float2bfloat16(o);
  }
}

// ---------------- residual + sum(NS slabs) + LN (writes f32 x and bf16 xb) ----------------
template <int NS>
__global__ __launch_bounds__(256) void add_ln_kernel(
    const float* __restrict__ resid, const float* __restrict__ t,
    const float* __restrict__ g, const float* __restrict__ bta,
    float* __restrict__ out, __hip_bfloat16* __restrict__ outb) {
  __shared__ float red[256];
  int tok = blockIdx.x;
  float vals[3];
  #pragma unroll
  for (int i = 0; i < 3; i++) {
    size_t idx = (size_t)tok * H + threadIdx.x + i * 256;
    float v = resid[idx];
    #pragma unroll
    for (int z = 0; z < NS; z++) v += t[z * MHc + idx];
    vals[i] = v;
  }
  float mean = block_sum256(vals[0] + vals[1] + vals[2], red) * (1.0f / H);
  float sq = 0.f;
  #pragma unroll
  for (int i = 0; i < 3; i++) { float d = vals[i] - mean; sq += d * d; }
  float var = block_sum256(sq, red) * (1.0f / H);
  float inv = rsqrtf(var + 1e-12f);
  #pragma unroll
  for (int i = 0; i < 3; i++) {
    int hh = threadIdx.x + i * 256;
    float o = (vals[i] - mean) * inv * g[hh] + bta[hh];
    out[(size_t)tok * H + hh] = o;
    outb[(size_t)tok * H + hh] = __float2bfloat16(o);
  }
}

// ---------------- MFMA bf16 GEMM: C = epi(A @ Bt^T + bias) ----------------
// Round-1 proven structure: single-buffer BK=32, 2 barriers per K-step.
// EPI: 0 = f32 store (split-K slab per blockIdx.z); 1 = bf16 store;
//      2 = gelu + bf16 store; 3 = logits partials;
//      5 = fused QKV: col section 0 -> Cb (q), 1 -> Cb2 (k), 2 -> Cb3 as vt-transposed.
// SWZ: bijective XCD-aware block swizzle (only matters when N/128 % 8 != 0).
template <int K, int N, int EPI, int SPLIT = 1, bool SWZ = false>
__global__ __launch_bounds__(256) void mfma_gemm(
    const short* __restrict__ A, const short* __restrict__ Bt,
    const float* __restrict__ bias,
    float* __restrict__ Cf, __hip_bfloat16* __restrict__ Cb,
    const int* __restrict__ labels, float2* __restrict__ partials,
    float* __restrict__ lablogit,
    __hip_bfloat16* __restrict__ Cb2, __hip_bfloat16* __restrict__ Cb3,
    const float* __restrict__ bias2, const float* __restrict__ bias3) {
  __shared__ __align__(16) short lds_a[128 * 32];
  __shared__ __align__(16) short lds_b[128 * 32];
  const int tid = threadIdx.x, lane = tid & 63, w = tid >> 6;
  const int wm = w >> 1, wn = w & 1;
  const int g = lane >> 4, c16 = lane & 15;
  const int srow = w * 32 + (lane >> 2);
  const int schunk = lane & 3;

  int bx = blockIdx.x, by = blockIdx.y;
  if constexpr (SWZ) {
    constexpr int NBX = N / 128;
    constexpr int GR = M / 128;          // 32 row tiles
    constexpr int NWG = NBX * GR;        // must be % 8 == 0
    static_assert(NWG % 8 == 0, "swizzle needs nwg %% 8 == 0");
    int lid = by * NBX + bx;
    int j = (lid & 7) * (NWG >> 3) + (lid >> 3);
    bx = j / GR; by = j % GR;
  }
  const int row0 = by * 128, col0 = bx * 128;

  floatx4 acc[4][4] = {};

  constexpr int Ks = K / SPLIT;
  const int koff = (SPLIT > 1) ? (int)blockIdx.z * Ks : 0;

  for (int k0 = koff; k0 < koff + Ks; k0 += 32) {
    #pragma unroll
    for (int j = 0; j < 2; j++) {
      int m = srow + j * 16;
      int cg = schunk ^ ((m >> 1) & 3);
      gload16(A + (size_t)(row0 + m) * K + (k0 + cg * 8), lds_a + w * 1024 + j * 512);
      gload16(Bt + (size_t)(col0 + m) * K + (k0 + cg * 8), lds_b + w * 1024 + j * 512);
    }
    __syncthreads();
    short8 af[4], bfr[4];
    #pragma unroll
    for (int t = 0; t < 4; t++) {
      int rm = wm * 64 + t * 16 + c16;
      af[t] = *(const short8*)(lds_a + rm * 32 + ((g ^ ((rm >> 1) & 3)) << 3));
      int rn = wn * 64 + t * 16 + c16;
      bfr[t] = *(const short8*)(lds_b + rn * 32 + ((g ^ ((rn >> 1) & 3)) << 3));
    }
    #pragma unroll
    for (int mt = 0; mt < 4; mt++)
      #pragma unroll
      for (int nt = 0; nt < 4; nt++)
        acc[mt][nt] = __builtin_amdgcn_mfma_f32_16x16x32_bf16(af[mt], bfr[nt], acc[mt][nt], 0, 0, 0);
    __syncthreads();
  }

  if constexpr (EPI == 0) {
    float* Cfz = Cf + (size_t)blockIdx.z * ((size_t)M * N);
    #pragma unroll
    for (int mt = 0; mt < 4; mt++)
      #pragma unroll
      for (int r = 0; r < 4; r++) {
        int row = row0 + wm * 64 + mt * 16 + g * 4 + r;
        #pragma unroll
        for (int nt = 0; nt < 4; nt++) {
          int col = col0 + wn * 64 + nt * 16 + c16;
          float bb = (SPLIT == 1 || blockIdx.z == 0) ? bias[col] : 0.f;
          Cfz[(size_t)row * N + col] = acc[mt][nt][r] + bb;
        }
      }
  } else if constexpr (EPI == 1 || EPI == 2) {
    #pragma unroll
    for (int mt = 0; mt < 4; mt++)
      #pragma unroll
      for (int r = 0; r < 4; r++) {
        int row = row0 + wm * 64 + mt * 16 + g * 4 + r;
        #pragma unroll
        for (int nt = 0; nt < 4; nt++) {
          int col = col0 + wn * 64 + nt * 16 + c16;
          float vv = acc[mt][nt][r] + bias[col];
          if constexpr (EPI == 2) vv = geluf(vv);
          Cb[(size_t)row * N + col] = __float2bfloat16(vv);
        }
      }
  } else if constexpr (EPI == 5) {
    // fused QKV: whole 128-col block lies within one section (768 % 128 == 0)
    const int sect = col0 / H;           // 0=q, 1=k, 2=v
    const int lc0 = col0 - sect * H;
    if (sect < 2) {
      __hip_bfloat16* out = (sect == 0) ? Cb : Cb2;
      const float* bptr = (sect == 0) ? bias : bias2;
      #pragma unroll
      for (int mt = 0; mt < 4; mt++)
        #pragma unroll
        for (int r = 0; r < 4; r++) {
          int row = row0 + wm * 64 + mt * 16 + g * 4 + r;
          #pragma unroll
          for (int nt = 0; nt < 4; nt++) {
            int lc = lc0 + wn * 64 + nt * 16 + c16;
            out[(size_t)row * H + lc] = __float2bfloat16(acc[mt][nt][r] + bptr[lc]);
          }
        }
    } else {
      unsigned short* vt = (unsigned short*)Cb3;
      #pragma unroll
      for (int mt = 0; mt < 4; mt++) {
        int row = row0 + wm * 64 + mt * 16 + g * 4;   // token for r=0
        int bb = row >> 9, s0 = row & 511;
        #pragma unroll
        for (int nt = 0; nt < 4; nt++) {
          int lc = lc0 + wn * 64 + nt * 16 + c16;
          int h = lc >> 6, d = lc & 63;
          float bcol = bias3[lc];
          uint2 u;
          unsigned short p0 = f2bf(acc[mt][nt][0] + bcol);
          unsigned short p1 = f2bf(acc[mt][nt][1] + bcol);
          unsigned short p2 = f2bf(acc[mt][nt][2] + bcol);
          unsigned short p3 = f2bf(acc[mt][nt][3] + bcol);
          u.x = (unsigned int)p0 | ((unsigned int)p1 << 16);
          u.y = (unsigned int)p2 | ((unsigned int)p3 << 16);
          *(uint2*)(vt + ((size_t)((bb * NH + h) * DH + d) << 9) + s0) = u;
        }
      }
    }
  } else {
    #pragma unroll
    for (int mt = 0; mt < 4; mt++)
      #pragma unroll
      for (int r = 0; r < 4; r++) {
        int row = row0 + wm * 64 + mt * 16 + g * 4 + r;
        int lab = labels[row];
        float vals[4];
        float rmax = -1e30f;
        #pragma unroll
        for (int nt = 0; nt < 4; nt++) {
          int col = col0 + wn * 64 + nt * 16 + c16;
          float vv = (col < V) ? (acc[mt][nt][r] + bias[col]) : -60000.0f;
          vals[nt] = vv;
          rmax = fmaxf(rmax, vv);
          if (col == lab) lablogit[row] = vv;
        }
        #pragma unroll
        for (int d = 1; d < 16; d <<= 1) rmax = fmaxf(rmax, __shfl_xor(rmax, d, 64));
        float se = 0.f;
        #pragma unroll
        for (int nt = 0; nt < 4; nt++) se += __expf(vals[nt] - rmax);
        #pragma unroll
        for (int d = 1; d < 16; d <<= 1) se += __shfl_xor(se, d, 64);
        if (c16 == 0)
          partials[(size_t)row * NT64 + (col0 >> 6) + wn] = make_float2(rmax, se);
      }
  }
}

// ---------------- MFMA flash attention ----------------
// XCD-locality remap: lid = x + 8y + 96z; hb = lid % 96 (96 % 8 == 0, so all 8
// q-tiles sharing one (b,h)'s K/V land on the same XCD under round-robin
// dispatch); qt = lid / 96. Bijective and load-balanced.
__global__ __launch_bounds__(256) void flash_attn(
    const short* __restrict__ q, const short* __restrict__ k,
    const short* __restrict__ vt, const int* __restrict__ sep,
    __hip_bfloat16* __restrict__ ctx) {
  constexpr int KT = 128;
  __shared__ __align__(16) short Qs[64 * 64];
  __shared__ __align__(16) short Ks[128 * 64];
  __shared__ __align__(16) short Vts[64 * 128];
  __shared__ __align__(16) short Pb[64 * 136];
  __shared__ __align__(16) float wm4[4][64];
  __shared__ __align__(16) float wl4[4][64];
  __shared__ __align__(16) float m_run[64], l_run[64], alpha_s[64], mnew_s[64];

  const int tid = threadIdx.x, lane = tid & 63, w = tid >> 6;
  const int g = lane >> 4, c16 = lane & 15;
  const int lid = blockIdx.x + 8 * (blockIdx.y + 12 * blockIdx.z);
  const int hb = lid % 96;
  const int h = hb % NH, b = hb / NH;
  const int qt0 = (lid / 96) * 64;
  const int sepb = sep[b];

  if (tid < 64) { m_run[tid] = -1e30f; l_run[tid] = 0.f; }

  // stage Q tile [64 q][64 d], chunk-swizzled: slot = c ^ (row&7)
  #pragma unroll
  for (int t = 0; t < 2; t++) {
    int id = (w * 2 + t) * 64 + lane;
    int row = id >> 3, slot = id & 7;
    int c = slot ^ (row & 7);
    gload16(q + (size_t)(b * S + qt0 + row) * H + h * DH + c * 8,
            Qs + (w * 2 + t) * 512);
  }

  int niter = (qt0 + 64 + KT - 1) / KT;
  int sepit = (sepb >> 7) + 1;
  if (sepit > niter) niter = sepit;

  floatx4 accO[4] = {};
  short8 qf[4][2];

  for (int it = 0; it < niter; ++it) {
    int kk0 = it * KT;
    __syncthreads();   // prev iteration's LDS reads complete
    #pragma unroll
    for (int t = 0; t < 4; t++) {
      int id = (w * 4 + t) * 64 + lane;
      {
        int row = id >> 3, slot = id & 7, c = slot ^ (row & 7);
        gload16(k + (size_t)(b * S + kk0 + row) * H + h * DH + c * 8,
                Ks + (w * 4 + t) * 512);
      }
      {
        int row = id >> 4, slot = id & 15, c = slot ^ (row & 15);
        gload16(vt + (size_t)((b * NH + h) * DH + row) * S + kk0 + c * 8,
                Vts + (w * 4 + t) * 512);
      }
    }
    __syncthreads();   // staging complete (drains vmcnt)

    if (it == 0) {
      #pragma unroll
      for (int nt = 0; nt < 4; nt++)
        #pragma unroll
        for (int st = 0; st < 2; st++) {
          int qq = nt * 16 + c16;
          int slot = (st * 4 + g) ^ (qq & 7);
          qf[nt][st] = *(const short8*)(Qs + qq * 64 + slot * 8);
        }
    }

    // Sc^T [128 kk][64 q]
    floatx4 accS[2][4] = {};
    #pragma unroll
    for (int st = 0; st < 2; st++) {
      short8 af[2];
      #pragma unroll
      for (int mt = 0; mt < 2; mt++) {
        int kkr = w * 32 + mt * 16 + c16;
        int slot = (st * 4 + g) ^ (kkr & 7);
        af[mt] = *(const short8*)(Ks + kkr * 64 + slot * 8);
      }
      #pragma unroll
      for (int mt = 0; mt < 2; mt++)
        #pragma unroll
        for (int nt = 0; nt < 4; nt++)
          accS[mt][nt] = __builtin_amdgcn_mfma_f32_16x16x32_bf16(
              af[mt], qf[nt][st], accS[mt][nt], 0, 0, 0);
    }

    // mask + scale; per-lane max per q
    float sc[2][4][4];
    float pm[4] = {-1e30f, -1e30f, -1e30f, -1e30f};
    #pragma unroll
    for (int mt = 0; mt < 2; mt++)
      #pragma unroll
      for (int nt = 0; nt < 4; nt++)
        #pragma unroll
        for (int r = 0; r < 4; r++) {
          int kkg = kk0 + w * 32 + mt * 16 + g * 4 + r;
          int qg = qt0 + nt * 16 + c16;
          bool allowed = (kkg <= qg) || (qg <= sepb && kkg <= sepb);
          float vv = accS[mt][nt][r] * 0.125f + (allowed ? 0.f : -1e4f);
          sc[mt][nt][r] = vv;
          pm[nt] = fmaxf(pm[nt], vv);
        }
    #pragma unroll
    for (int nt = 0; nt < 4; nt++) {
      pm[nt] = fmaxf(pm[nt], __shfl_xor(pm[nt], 16, 64));
      pm[nt] = fmaxf(pm[nt], __shfl_xor(pm[nt], 32, 64));
    }
    if (lane < 16) {
      #pragma unroll
      for (int nt = 0; nt < 4; nt++) wm4[w][nt * 16 + c16] = pm[nt];
    }
    __syncthreads();
    if (tid < 64) {
      float mit = fmaxf(fmaxf(wm4[0][tid], wm4[1][tid]), fmaxf(wm4[2][tid], wm4[3][tid]));
      float mold = m_run[tid];
      float mnew = fmaxf(mold, mit);
      float al = __expf(mold - mnew);
      m_run[tid] = mnew;
      alpha_s[tid] = al;
      mnew_s[tid] = mnew;
      l_run[tid] *= al;
    }
    __syncthreads();

    // P = exp(sc - mnew); write P^T to Pb[q][kk]
    float psum[4] = {};
    #pragma unroll
    for (int mt = 0; mt < 2; mt++)
      #pragma unroll
      for (int nt = 0; nt < 4; nt++) {
        int qg = nt * 16 + c16;
        float mn = mnew_s[qg];
        unsigned short pk[4];
        #pragma unroll
        for (int r = 0; r < 4; r++) {
          float p = __expf(sc[mt][nt][r] - mn);
          psum[nt] += p;
          pk[r] = f2bf(p);
        }
        int kb = w * 32 + mt * 16 + g * 4;
        uint2 u;
        u.x = (unsigned int)pk[0] | ((unsigned int)pk[1] << 16);
        u.y = (unsigned int)pk[2] | ((unsigned int)pk[3] << 16);
        *(uint2*)(Pb + qg * 136 + kb) = u;
      }
    #pragma unroll
    for (int nt = 0; nt < 4; nt++) {
      psum[nt] += __shfl_xor(psum[nt], 16, 64);
      psum[nt] += __shfl_xor(psum[nt], 32, 64);
    }
    if (lane < 16) {
      #pragma unroll
      for (int nt = 0; nt < 4; nt++) wl4[w][nt * 16 + c16] = psum[nt];
    }
    {
      float4 a4 = *(const float4*)(alpha_s + w * 16 + g * 4);
      #pragma unroll
      for (int nt = 0; nt < 4; nt++) {
        accO[nt][0] *= a4.x; accO[nt][1] *= a4.y;
        accO[nt][2] *= a4.z; accO[nt][3] *= a4.w;
      }
    }
    __syncthreads();   // Pb + wl4 visible
    if (tid < 64)
      l_run[tid] += wl4[0][tid] + wl4[1][tid] + wl4[2][tid] + wl4[3][tid];

    // O[64 q][64 d] += P · V^T
    #pragma unroll
    for (int st = 0; st < 4; st++) {
      short8 pf = *(const short8*)(Pb + (w * 16 + c16) * 136 + st * 32 + g * 8);
      #pragma unroll
      for (int nt = 0; nt < 4; nt++) {
        int d = nt * 16 + c16;
        int slot = (st * 4 + g) ^ (d & 15);
        short8 vf = *(const short8*)(Vts + d * 128 + slot * 8);
        accO[nt] = __builtin_amdgcn_mfma_f32_16x16x32_bf16(pf, vf, accO[nt], 0, 0, 0);
      }
    }
  }

  __syncthreads();
  float4 lv = *(const float4*)(l_run + w * 16 + g * 4);
  float linv[4] = {1.0f / lv.x, 1.0f / lv.y, 1.0f / lv.z, 1.0f / lv.w};
  #pragma unroll
  for (int r = 0; r < 4; r++) {
    int row = b * S + qt0 + w * 16 + g * 4 + r;
    #pragma unroll
    for (int nt = 0; nt < 4; nt++)
      ctx[(size_t)row * H + h * DH + nt * 16 + c16] =
          __float2bfloat16(accO[nt][r] * linv[r]);
  }
}

// ---------------- per-token nll + accumulate ----------------
__global__ __launch_bounds__(256) void loss_kernel(
    const float2* __restrict__ partials, const float* __restrict__ lablogit,
    const int* __restrict__ labels, float* __restrict__ acc) {
  int tok = blockIdx.x;
  if (labels[tok] < 0) return;
  __shared__ float red[256];
  float lm = -1e30f;
  for (int t = threadIdx.x; t < NT64; t += 256)
    lm = fmaxf(lm, partials[(size_t)tok * NT64 + t].x);
  float Mx = block_max256(lm, red);
  float ls = 0.f;
  for (int t = threadIdx.x; t < NT64; t += 256) {
    float2 p = partials[(size_t)tok * NT64 + t];
    ls += p.y * __expf(p.x - Mx);
  }
  float Ssum = block_sum256(ls, red);
  if (threadIdx.x == 0) {
    float nll = (Mx + logf(Ssum)) - lablogit[tok];
    atomicAdd(&acc[0], nll);
    atomicAdd(&acc[1], 1.0f);
  }
}

__global__ void finalize_kernel(const float* __restrict__ acc, float* __restrict__ out) {
  out[0] = acc[0] / fmaxf(acc[1], 1.0f);
}

}  // namespace

extern "C" void kernel_launch(void* const* d_in, const int* in_sizes, int n_in,
                              void* d_out, int out_size, void* d_ws, size_t ws_size,
                              hipStream_t stream) {
  const int*   input_ids = (const int*)d_in[0];
  const int*   labels    = (const int*)d_in[1];
  const float* word_emb  = (const float*)d_in[2];
  const float* pos_emb   = (const float*)d_in[3];
  const float* type_emb  = (const float*)d_in[4];
  const float* emb_ln_g  = (const float*)d_in[5];
  const float* emb_ln_b  = (const float*)d_in[6];
  const float* Wq = (const float*)d_in[7];
  const float* bq = (const float*)d_in[8];
  const float* Wk = (const float*)d_in[9];
  const float* bk = (const float*)d_in[10];
  const float* Wv = (const float*)d_in[11];
  const float* bv = (const float*)d_in[12];
  const float* Wo = (const float*)d_in[13];
  const float* bo = (const float*)d_in[14];
  const float* ln1_g = (const float*)d_in[15];
  const float* ln1_b = (const float*)d_in[16];
  const float* Wi = (const float*)d_in[17];
  const float* bi = (const float*)d_in[18];
  const float* Wd = (const float*)d_in[19];
  const float* bd = (const float*)d_in[20];
  const float* ln2_g = (const float*)d_in[21];
  const float* ln2_b = (const float*)d_in[22];
  const float* Wc = (const float*)d_in[23];
  const float* bc = (const float*)d_in[24];

  char* base = (char*)d_ws;
  size_t off = 0;
  auto alloc = [&](size_t bytes) -> void* {
    void* p = base + off;
    off = (off + bytes + 255) & ~(size_t)255;
    return p;
  };
  const size_t MH = (size_t)M * H;
  float*          x        = (float*)alloc(MH * 4);
  float*          t2       = (float*)alloc(MH * 4 * 4);     // 4 split-K slabs
  __hip_bfloat16* xb       = (__hip_bfloat16*)alloc(MH * 2);
  __hip_bfloat16* qb       = (__hip_bfloat16*)alloc(MH * 2);
  __hip_bfloat16* kb       = (__hip_bfloat16*)alloc(MH * 2);
  __hip_bfloat16* vt       = (__hip_bfloat16*)alloc((size_t)B * NH * DH * S * 2);
  __hip_bfloat16* ctxb     = (__hip_bfloat16*)alloc(MH * 2);
  __hip_bfloat16* t1b      = (__hip_bfloat16*)alloc((size_t)M * FF * 2);
  float2*         partials = (float2*)alloc((size_t)M * NT64 * 8);
  float*          lablogit = (float*)alloc((size_t)M * 4);
  float*          acc      = (float*)alloc(2 * 4);
  int*            sep      = (int*)alloc(B * 4);
  __hip_bfloat16* wqkv_t = (__hip_bfloat16*)alloc((size_t)LAYERS * QKVN * H * 2);
  __hip_bfloat16* wo_t = (__hip_bfloat16*)alloc((size_t)LAYERS * H * H * 2);
  __hip_bfloat16* wi_t = (__hip_bfloat16*)alloc((size_t)FF * H * 2);
  __hip_bfloat16* wd_t = (__hip_bfloat16*)alloc((size_t)H * FF * 2);
  __hip_bfloat16* wc_t = (__hip_bfloat16*)alloc((size_t)NPAD * H * 2);

  hipMemsetAsync(acc, 0, 2 * sizeof(float), stream);

  sep_kernel<<<B, 256, 0, stream>>>(input_ids, sep);
  embed_kernel<<<M, 256, 0, stream>>>(input_ids, word_emb, pos_emb, type_emb,
                                      emb_ln_g, emb_ln_b, x, xb);

  {
    dim3 tg(H / 32, H / 32, LAYERS);
    // fused QKV weight buffer: per layer rows [0,768)=Wq cols, [768,1536)=Wk, [1536,2304)=Wv
    transpose_kernel<<<tg, 256, 0, stream>>>(Wq, wqkv_t, H, H, H,
                                             (size_t)H * H, (size_t)QKVN * H);
    transpose_kernel<<<tg, 256, 0, stream>>>(Wk, wqkv_t + (size_t)H * H, H, H, H,
                                             (size_t)H * H, (size_t)QKVN * H);
    transpose_kernel<<<tg, 256, 0, stream>>>(Wv, wqkv_t + (size_t)2 * H * H, H, H, H,
                                             (size_t)H * H, (size_t)QKVN * H);
    transpose_kernel<<<tg, 256, 0, stream>>>(Wo, wo_t, H, H, H, (size_t)H * H, (size_t)H * H);
    dim3 tgc(H / 32, NPAD / 32, 1);
    transpose_kernel<<<tgc, 256, 0, stream>>>(Wc, wc_t, H, V, NPAD, 0, 0);
  }

  dim3 gQKV(QKVN / 128, M / 128);      // (18, 32) = 576 blocks
  dim3 gO(H / 128, M / 128, 2);        // split-K x2: 384 blocks
  dim3 gF(FF / 128, M / 128);          // (24, 32) = 768 blocks
  dim3 gD(H / 128, M / 128, 4);        // split-K x4: 768 blocks
  dim3 gAttn(S / 64, NH, B);           // 768 blocks

  for (int l = 0; l < LAYERS; l++) {
    transpose_kernel<<<dim3(H / 32, FF / 32, 1), 256, 0, stream>>>(
        Wi + (size_t)l * H * FF, wi_t, H, FF, FF, 0, 0);
    transpose_kernel<<<dim3(FF / 32, H / 32, 1), 256, 0, stream>>>(
        Wd + (size_t)l * FF * H, wd_t, FF, H, H, 0, 0);

    const short* xbs = (const short*)xb;
    // fused QKV: one GEMM, N=2304
    mfma_gemm<H, QKVN, 5><<<gQKV, 256, 0, stream>>>(
        xbs, (const short*)(wqkv_t + (size_t)l * QKVN * H), bq + (size_t)l * H,
        nullptr, qb, nullptr, nullptr, nullptr,
        kb, vt, bk + (size_t)l * H, bv + (size_t)l * H);
    flash_attn<<<gAttn, 256, 0, stream>>>(
        (const short*)qb, (const short*)kb, (const short*)vt, sep, ctxb);
    // O projection, split-K x2 into slabs t2[0..1]
    mfma_gemm<H, H, 0, 2><<<gO, 256, 0, stream>>>(
        (const short*)ctxb, (const short*)(wo_t + (size_t)l * H * H), bo + (size_t)l * H,
        t2, nullptr, nullptr, nullptr, nullptr,
        nullptr, nullptr, nullptr, nullptr);
    add_ln_kernel<2><<<M, 256, 0, stream>>>(x, t2, ln1_g + (size_t)l * H,
                                            ln1_b + (size_t)l * H, x, xb);
    mfma_gemm<H, FF, 2><<<gF, 256, 0, stream>>>(
        (const short*)xb, (const short*)wi_t, bi + (size_t)l * FF,
        nullptr, t1b, nullptr, nullptr, nullptr,
        nullptr, nullptr, nullptr, nullptr);
    // FFN down projection, split-K x4 into slabs t2[0..3]
    mfma_gemm<FF, H, 0, 4><<<gD, 256, 0, stream>>>(
        (const short*)t1b, (const short*)wd_t, bd + (size_t)l * H,
        t2, nullptr, nullptr, nullptr, nullptr,
        nullptr, nullptr, nullptr, nullptr);
    add_ln_kernel<4><<<M, 256, 0, stream>>>(x, t2, ln2_g + (size_t)l * H,
                                            ln2_b + (size_t)l * H, x, xb);
  }

  dim3 gV(NPAD / 128, M / 128);  // (166, 32)
  mfma_gemm<H, NPAD, 3, 1, true><<<gV, 256, 0, stream>>>(
      (const short*)xb, (const short*)wc_t, bc,
      nullptr, nullptr, labels, partials, lablogit,
      nullptr, nullptr, nullptr, nullptr);
  loss_kernel<<<M, 256, 0, stream>>>(partials, lablogit, labels, acc);
  finalize_kernel<<<1, 1, 0, stream>>>(acc, (float*)d_out);
}